// Round 5
// baseline (96.655 us; speedup 1.0000x reference)
//
#include <hip/hip_runtime.h>

// FlashAttention fwd: B=2, S=2048, H=16, D=64, fp32 in/out, non-causal.
// R4: KV-split x2 for occupancy (grid 1024 -> 4 blocks/CU, 16 waves/CU).
// P kept in-register (shfl_xor(32) pairwise exchange, no LDS P buffer) ->
// LDS 32KB. Prep converts K->bf16 [b][h][s][d], V->bf16^T [b][h][d][s];
// attn stages via global_load_lds (pre-swizzled source, double-buffered);
// merge kernel combines the two splits' (O,m,l) partials.

#define S_  2048
#define HH  16
#define DD  64
#define QT  128
#define KT  64
#define SR  1024   // H*D floats per token row

typedef __attribute__((ext_vector_type(8)))  short short8;
typedef __attribute__((ext_vector_type(16))) float f32x16;
typedef __attribute__((ext_vector_type(2)))  unsigned uint2v;

__device__ __forceinline__ unsigned short f2bf(float f) {
    unsigned int u = __float_as_uint(f);
    u += 0x7fffu + ((u >> 16) & 1u);   // RNE
    return (unsigned short)(u >> 16);
}

__device__ __forceinline__ unsigned pkbf(float lo, float hi) {
    unsigned r;
    asm("v_cvt_pk_bf16_f32 %0, %1, %2" : "=v"(r) : "v"(lo), "v"(hi));
    return r;
}

__device__ __forceinline__ short8 cvt8(float4 a, float4 b) {
    union { unsigned u[4]; short8 v; } r;
    r.u[0] = pkbf(a.x, a.y); r.u[1] = pkbf(a.z, a.w);
    r.u[2] = pkbf(b.x, b.y); r.u[3] = pkbf(b.z, b.w);
    return r.v;
}

__device__ __forceinline__ f32x16 mfma32(short8 a, short8 b, f32x16 c) {
    return __builtin_amdgcn_mfma_f32_32x32x16_bf16(a, b, c, 0, 0, 0);
}

__device__ __forceinline__ void gload16(const void* g, void* l) {
    __builtin_amdgcn_global_load_lds(
        (const __attribute__((address_space(1))) void*)g,
        (__attribute__((address_space(3))) void*)l, 16, 0, 0);
}

// ---------------- prep kernels (R3-verified) ----------------

__global__ __launch_bounds__(256)
void prep_k(const float* __restrict__ k, short* __restrict__ kb) {
    const int gid = blockIdx.x * 256 + threadIdx.x;   // 524288 total
    const int d0 = (gid & 7) * 8;
    const int s  = (gid >> 3) & (S_ - 1);
    const int h  = (gid >> 14) & (HH - 1);
    const int b  = gid >> 18;
    const float* src = k + ((size_t)(b * S_ + s) * SR + h * DD + d0);
    float4 a = *(const float4*)src, bb = *(const float4*)(src + 4);
    *(short8*)&kb[((size_t)(b * HH + h) * S_ + s) * DD + d0] = cvt8(a, bb);
}

__global__ __launch_bounds__(256)
void prep_vt(const float* __restrict__ v, short* __restrict__ vt) {
    __shared__ short lt[KT][72];   // +8 pad
    const int t = blockIdx.x & 31;
    const int h = (blockIdx.x >> 5) & 15;
    const int b = blockIdx.x >> 9;
    const int tid = threadIdx.x;
    const int c8 = tid & 7, r0 = tid >> 3;
    #pragma unroll
    for (int rr = 0; rr < 2; ++rr) {
        const int row = r0 + rr * 32;
        const float* src = v + ((size_t)(b * S_ + t * KT + row) * SR + h * DD + c8 * 8);
        float4 a = *(const float4*)src, bb = *(const float4*)(src + 4);
        *(short8*)&lt[row][c8 * 8] = cvt8(a, bb);
    }
    __syncthreads();
    const int d = tid >> 2, q4 = tid & 3;
    short tmp[16];
    #pragma unroll
    for (int i = 0; i < 16; ++i) tmp[i] = lt[q4 * 16 + i][d];
    short8* dst = (short8*)&vt[((size_t)(b * HH + h) * DD + d) * S_ + t * KT + q4 * 16];
    dst[0] = *(short8*)&tmp[0];
    dst[1] = *(short8*)&tmp[8];
}

// ---------------- split attention kernel ----------------

__global__ __launch_bounds__(256, 4)
void fattn_split(const float* __restrict__ q, const short* __restrict__ kb,
                 const short* __restrict__ vtb, float* __restrict__ opart,
                 float* __restrict__ mlbuf) {
    __shared__ short lk[2][KT * DD];    // K[kv][d], granule g holds chunk g^(kv&7)
    __shared__ short lvT[2][DD * KT];   // V^T[d][kv], granule g holds kv-chunk g^(d&7)

    const int tid  = threadIdx.x;
    const int lane = tid & 63;
    const int w    = tid >> 6;
    const int c    = lane & 31;
    const int hi   = lane >> 5;

    // XCD swizzle: 1024 blocks = 8 XCDs x 128; a 128-chunk covers 4 (b,h)
    // groups (4MB Kb+VTb = one XCD L2).
    const int bid0 = blockIdx.x;
    const int bid  = ((bid0 & 7) << 7) | (bid0 >> 3);
    const int split = bid & 1;
    const int qt  = (bid >> 1) & 15;
    const int h   = (bid >> 5) & 15;
    const int b   = (bid >> 9) & 1;
    const int bh  = b * HH + h;

    const int qrow = qt * QT + w * 32 + c;
    const float sc = 0.125f * 1.4426950408889634f;  // D^-1/2 * log2(e)

    // ---- Q B-fragments: qf[kc][i] = Q[qrow][kc*16 + hi*8 + i] * sc ----
    short8 qf[4];
    {
        const float* qp = q + (size_t)(b * S_ + qrow) * SR + h * DD;
        #pragma unroll
        for (int kc = 0; kc < 4; ++kc) {
            const int d0 = kc * 16 + hi * 8;
            float4 a = *(const float4*)(qp + d0);
            float4 bb = *(const float4*)(qp + d0 + 4);
            a.x *= sc; a.y *= sc; a.z *= sc; a.w *= sc;
            bb.x *= sc; bb.y *= sc; bb.z *= sc; bb.w *= sc;
            qf[kc] = cvt8(a, bb);
        }
    }

    f32x16 o0, o1;
    #pragma unroll
    for (int i = 0; i < 16; ++i) { o0[i] = 0.f; o1[i] = 0.f; }
    float m_run = -1e30f, l_run = 0.f;

    const short* kbh = kb  + (size_t)bh * S_ * DD;
    const short* vbh = vtb + (size_t)bh * DD * S_;
    const int r8 = lane >> 3;
    const int g8 = lane & 7;
    const int t0 = split * 16;

    #define STAGE(tg_, bufi_)                                                  \
        _Pragma("unroll")                                                      \
        for (int ss = 0; ss < 2; ++ss) {                                       \
            const int sect = 2 * w + ss;                                       \
            const int row  = sect * 8 + r8;                                    \
            gload16(kbh + (size_t)((tg_) * KT + row) * DD + ((g8 ^ (row & 7)) * 8), \
                    &lk[bufi_][sect * 512]);                                   \
            gload16(vbh + (size_t)row * S_ + (tg_) * KT + ((g8 ^ (row & 7)) * 8),   \
                    &lvT[bufi_][sect * 512]);                                  \
        }

    STAGE(t0, 0);

    for (int tt = 0; tt < 16; ++tt) {
        const int cur = tt & 1;
        __syncthreads();   // drains this tile's loads; prev tile reads done
        if (tt + 1 < 16) { STAGE(t0 + tt + 1, cur ^ 1); }

        // ---- S^T = K . Q^T : lane holds S[q=c][kv=(r&3)+8*(r>>2)+4*hi (+32)] ----
        f32x16 s0, s1;
        #pragma unroll
        for (int i = 0; i < 16; ++i) { s0[i] = 0.f; s1[i] = 0.f; }
        __builtin_amdgcn_s_setprio(1);
        #pragma unroll
        for (int kc = 0; kc < 4; ++kc) {
            const int ch = 2 * kc + hi;
            short8 kf0 = *(const short8*)&lk[cur][c * 64 + ((ch ^ (c & 7)) * 8)];
            short8 kf1 = *(const short8*)&lk[cur][(32 + c) * 64 + ((ch ^ (c & 7)) * 8)];
            s0 = mfma32(kf0, qf[kc], s0);
            s1 = mfma32(kf1, qf[kc], s1);
        }
        __builtin_amdgcn_s_setprio(0);

        // ---- pmax (balanced tree) ----
        float q0_ = fmaxf(fmaxf(s0[0], s0[1]),  fmaxf(s0[2], s0[3]));
        float q1_ = fmaxf(fmaxf(s0[4], s0[5]),  fmaxf(s0[6], s0[7]));
        float q2_ = fmaxf(fmaxf(s0[8], s0[9]),  fmaxf(s0[10], s0[11]));
        float q3_ = fmaxf(fmaxf(s0[12], s0[13]), fmaxf(s0[14], s0[15]));
        float q4_ = fmaxf(fmaxf(s1[0], s1[1]),  fmaxf(s1[2], s1[3]));
        float q5_ = fmaxf(fmaxf(s1[4], s1[5]),  fmaxf(s1[6], s1[7]));
        float q6_ = fmaxf(fmaxf(s1[8], s1[9]),  fmaxf(s1[10], s1[11]));
        float q7_ = fmaxf(fmaxf(s1[12], s1[13]), fmaxf(s1[14], s1[15]));
        float pmax = fmaxf(fmaxf(fmaxf(q0_, q1_), fmaxf(q2_, q3_)),
                           fmaxf(fmaxf(q4_, q5_), fmaxf(q6_, q7_)));
        pmax = fmaxf(pmax, __shfl_xor(pmax, 32));

        if (__ballot(pmax > m_run + 8.0f)) {   // defer-max THR=8
            const float mn = fmaxf(m_run, pmax);
            const float corr = exp2f(m_run - mn);
            m_run = mn;
            l_run *= corr;
            #pragma unroll
            for (int i = 0; i < 16; ++i) { o0[i] *= corr; o1[i] *= corr; }
        }

        // ---- per-group: exp2 -> pack -> in-register P^T frag -> PV ----
        // Group g covers kv-local 32*g..+31; pairs pkA[sp]=(8sp+4hi,+1),
        // pkB[sp]=(8sp+4hi+2,+3). B-frag kc word exchange = lane<->lane+32.
        float rs = 0.f;
        #pragma unroll
        for (int gidx = 0; gidx < 2; ++gidx) {
            const f32x16& sg = gidx ? s1 : s0;
            float p[16];
            #pragma unroll
            for (int i = 0; i < 16; ++i) p[i] = exp2f(sg[i] - m_run);
            rs += (((p[0] + p[1]) + (p[2] + p[3])) + ((p[4] + p[5]) + (p[6] + p[7])))
                + (((p[8] + p[9]) + (p[10] + p[11])) + ((p[12] + p[13]) + (p[14] + p[15])));
            unsigned pA[4], pB[4];
            #pragma unroll
            for (int sp = 0; sp < 4; ++sp) {
                pA[sp] = pkbf(p[4 * sp + 0], p[4 * sp + 1]);
                pB[sp] = pkbf(p[4 * sp + 2], p[4 * sp + 3]);
            }
            union PU { unsigned u[4]; short8 v; } pf[2];
            {   // kcg = 0  (k-local 0..15)
                unsigned rA = __shfl_xor(hi ? pA[0] : pA[1], 32);
                unsigned rB = __shfl_xor(hi ? pB[0] : pB[1], 32);
                pf[0].u[0] = hi ? rA : pA[0];
                pf[0].u[1] = hi ? rB : pB[0];
                pf[0].u[2] = hi ? pA[1] : rA;
                pf[0].u[3] = hi ? pB[1] : rB;
            }
            {   // kcg = 1  (k-local 16..31)
                unsigned rA = __shfl_xor(hi ? pA[2] : pA[3], 32);
                unsigned rB = __shfl_xor(hi ? pB[2] : pB[3], 32);
                pf[1].u[0] = hi ? rA : pA[2];
                pf[1].u[1] = hi ? rB : pB[2];
                pf[1].u[2] = hi ? pA[3] : rA;
                pf[1].u[3] = hi ? pB[3] : rB;
            }
            // ---- O^T += V^T . P^T for this group's two k-chunks ----
            __builtin_amdgcn_s_setprio(1);
            #pragma unroll
            for (int kcg = 0; kcg < 2; ++kcg) {
                const int ch = 2 * gidx * 2 + 2 * kcg + hi;   // global k-chunk
                const int gsel = (ch ^ (c & 7)) * 8;
                short8 va0 = *(const short8*)&lvT[cur][c * 64 + gsel];
                short8 va1 = *(const short8*)&lvT[cur][(32 + c) * 64 + gsel];
                o0 = mfma32(va0, pf[kcg].v, o0);
                o1 = mfma32(va1, pf[kcg].v, o1);
            }
            __builtin_amdgcn_s_setprio(0);
        }
        rs += __shfl_xor(rs, 32);
        l_run += rs;
    }
    #undef STAGE

    // ---- Epilogue: unnormalized partials + (m,l) ----
    float* oprow = opart + ((size_t)((split * 2 + b) * S_ + qrow)) * SR + h * DD;
    #pragma unroll
    for (int sp = 0; sp < 4; ++sp) {
        float4 st0, st1;
        st0.x = o0[4 * sp + 0]; st0.y = o0[4 * sp + 1];
        st0.z = o0[4 * sp + 2]; st0.w = o0[4 * sp + 3];
        st1.x = o1[4 * sp + 0]; st1.y = o1[4 * sp + 1];
        st1.z = o1[4 * sp + 2]; st1.w = o1[4 * sp + 3];
        *(float4*)(oprow + 8 * sp + 4 * hi)      = st0;
        *(float4*)(oprow + 32 + 8 * sp + 4 * hi) = st1;
    }
    if (hi == 0) {
        float2 ml; ml.x = m_run; ml.y = l_run;
        ((float2*)mlbuf)[((size_t)(split * 2 + b) * HH + h) * S_ + qrow] = ml;
    }
}

// ---------------- merge kernel ----------------

__global__ __launch_bounds__(256)
void merge_k(const float* __restrict__ opart, const float* __restrict__ mlbuf,
             float* __restrict__ out) {
    const int t = blockIdx.x * 256 + threadIdx.x;   // 1048576 total
    const int d4 = (t & 15) * 4;
    const int h  = (t >> 4) & 15;
    const int qq = (t >> 8) & (S_ - 1);
    const int b  = t >> 19;
    const float2* mlp = (const float2*)mlbuf;
    const float2 ml0 = mlp[((size_t)(0 + b) * HH + h) * S_ + qq];
    const float2 ml1 = mlp[((size_t)(2 + b) * HH + h) * S_ + qq];
    const float M  = fmaxf(ml0.x, ml1.x);
    const float e0 = exp2f(ml0.x - M), e1 = exp2f(ml1.x - M);
    const float inv = 1.0f / (e0 * ml0.y + e1 * ml1.y);
    const size_t i0 = ((size_t)((0 + b) * S_ + qq)) * SR + h * DD + d4;
    const size_t i1 = ((size_t)((2 + b) * S_ + qq)) * SR + h * DD + d4;
    const float4 O0 = *(const float4*)(opart + i0);
    const float4 O1 = *(const float4*)(opart + i1);
    float4 r;
    r.x = (e0 * O0.x + e1 * O1.x) * inv;
    r.y = (e0 * O0.y + e1 * O1.y) * inv;
    r.z = (e0 * O0.z + e1 * O1.z) * inv;
    r.w = (e0 * O0.w + e1 * O1.w) * inv;
    *(float4*)(out + ((size_t)(b * S_ + qq)) * SR + h * DD + d4) = r;
}

// ---------------- fallback (R2-verified, used if ws too small) ----------------

__global__ __launch_bounds__(256, 2)
void fattn_fb(const float* __restrict__ q, const float* __restrict__ k,
              const float* __restrict__ v, float* __restrict__ out) {
    __shared__ short lk[KT * DD];
    __shared__ short lvT[DD * KT];
    __shared__ short lp[4][32 * KT];

    const int tid  = threadIdx.x;
    const int lane = tid & 63;
    const int w    = tid >> 6;
    const int c    = lane & 31;
    const int hi   = lane >> 5;

    const int bid = blockIdx.x;
    const int qt  = bid & 15;
    const int h   = (bid >> 4) & 15;
    const int b   = bid >> 8;

    const int qrow = qt * QT + w * 32 + c;
    const float sc = 0.125f * 1.4426950408889634f;

    short8 qf[4];
    {
        const float* qp = q + (size_t)(b * S_ + qrow) * SR + h * DD;
        #pragma unroll
        for (int kc = 0; kc < 4; ++kc) {
            const int d0 = kc * 16 + hi * 8;
            float4 a = *(const float4*)(qp + d0);
            float4 bb = *(const float4*)(qp + d0 + 4);
            a.x *= sc; a.y *= sc; a.z *= sc; a.w *= sc;
            bb.x *= sc; bb.y *= sc; bb.z *= sc; bb.w *= sc;
            qf[kc] = cvt8(a, bb);
        }
    }

    f32x16 o0, o1;
    #pragma unroll
    for (int i = 0; i < 16; ++i) { o0[i] = 0.f; o1[i] = 0.f; }
    float m_run = -1e30f, l_run = 0.f;

    const float* kb = k + (size_t)b * S_ * SR + h * DD;
    const float* vb = v + (size_t)b * S_ * SR + h * DD;

    for (int t = 0; t < S_ / KT; ++t) {
        __syncthreads();
        for (int cc = w; cc < 8; cc += 4) {
            const size_t gro = (size_t)(t * KT + lane) * SR + cc * 8;
            const float4* kp = (const float4*)(kb + gro);
            float4 k0 = kp[0], k1 = kp[1];
            *(short8*)&lk[lane * 64 + ((cc ^ (lane & 7)) * 8)] = cvt8(k0, k1);
            const float4* vp = (const float4*)(vb + gro);
            float4 v0 = vp[0], v1 = vp[1];
            float vv[8] = {v0.x, v0.y, v0.z, v0.w, v1.x, v1.y, v1.z, v1.w};
            #pragma unroll
            for (int i = 0; i < 8; ++i) {
                const int d = cc * 8 + i;
                lvT[d * 64 + (((lane >> 3) ^ (d & 7)) * 8) + (lane & 7)] =
                    (short)f2bf(vv[i]);
            }
        }
        __syncthreads();

        f32x16 s0, s1;
        #pragma unroll
        for (int i = 0; i < 16; ++i) { s0[i] = 0.f; s1[i] = 0.f; }
        #pragma unroll
        for (int kc = 0; kc < 4; ++kc) {
            const int ch = 2 * kc + hi;
            short8 kf0 = *(const short8*)&lk[c * 64 + ((ch ^ (c & 7)) * 8)];
            short8 kf1 = *(const short8*)&lk[(32 + c) * 64 + ((ch ^ (c & 7)) * 8)];
            s0 = mfma32(kf0, qf[kc], s0);
            s1 = mfma32(kf1, qf[kc], s1);
        }

        float pmax = fmaxf(s0[0], s0[1]);
        #pragma unroll
        for (int i = 2; i < 16; ++i) pmax = fmaxf(pmax, s0[i]);
        #pragma unroll
        for (int i = 0; i < 16; ++i) pmax = fmaxf(pmax, s1[i]);
        pmax = fmaxf(pmax, __shfl_xor(pmax, 32));

        if (__ballot(pmax > m_run + 8.0f)) {
            const float mn = fmaxf(m_run, pmax);
            const float corr = exp2f(m_run - mn);
            m_run = mn;
            l_run *= corr;
            #pragma unroll
            for (int i = 0; i < 16; ++i) { o0[i] *= corr; o1[i] *= corr; }
        }

        float p0[16], p1[16];
        float rs = 0.f;
        #pragma unroll
        for (int i = 0; i < 16; ++i) { p0[i] = exp2f(s0[i] - m_run); rs += p0[i]; }
        #pragma unroll
        for (int i = 0; i < 16; ++i) { p1[i] = exp2f(s1[i] - m_run); rs += p1[i]; }
        rs += __shfl_xor(rs, 32);
        l_run += rs;

        #pragma unroll
        for (int sp = 0; sp < 4; ++sp) {
            uint2v w0;
            w0[0] = pkbf(p0[4 * sp + 0], p0[4 * sp + 1]);
            w0[1] = pkbf(p0[4 * sp + 2], p0[4 * sp + 3]);
            *(uint2v*)&lp[w][c * 64 + ((sp ^ (c & 7)) * 8) + hi * 4] = w0;
            uint2v w1;
            w1[0] = pkbf(p1[4 * sp + 0], p1[4 * sp + 1]);
            w1[1] = pkbf(p1[4 * sp + 2], p1[4 * sp + 3]);
            *(uint2v*)&lp[w][c * 64 + (((4 + sp) ^ (c & 7)) * 8) + hi * 4] = w1;
        }

        #pragma unroll
        for (int kc = 0; kc < 4; ++kc) {
            const int gsel = ((2 * kc + hi) ^ (c & 7)) * 8;
            short8 pa  = *(const short8*)&lp[w][c * 64 + gsel];
            short8 va0 = *(const short8*)&lvT[c * 64 + gsel];
            short8 va1 = *(const short8*)&lvT[(32 + c) * 64 + gsel];
            o0 = mfma32(va0, pa, o0);
            o1 = mfma32(va1, pa, o1);
        }
    }

    const float inv = 1.0f / l_run;
    float* orow = out + (size_t)(b * S_ + qrow) * SR + h * DD;
    #pragma unroll
    for (int sp = 0; sp < 4; ++sp) {
        float4 st0, st1;
        st0.x = o0[4 * sp + 0] * inv; st0.y = o0[4 * sp + 1] * inv;
        st0.z = o0[4 * sp + 2] * inv; st0.w = o0[4 * sp + 3] * inv;
        st1.x = o1[4 * sp + 0] * inv; st1.y = o1[4 * sp + 1] * inv;
        st1.z = o1[4 * sp + 2] * inv; st1.w = o1[4 * sp + 3] * inv;
        *(float4*)(orow + 8 * sp + 4 * hi)      = st0;
        *(float4*)(orow + 32 + 8 * sp + 4 * hi) = st1;
    }
}

extern "C" void kernel_launch(void* const* d_in, const int* in_sizes, int n_in,
                              void* d_out, int out_size, void* d_ws, size_t ws_size,
                              hipStream_t stream) {
    const float* q = (const float*)d_in[0];
    const float* k = (const float*)d_in[1];
    const float* v = (const float*)d_in[2];
    float* out = (float*)d_out;

    const size_t elems  = (size_t)2 * HH * S_ * DD;          // 4.19M per tensor
    const size_t kvB    = elems * 2 * sizeof(short);         // Kb + VTb = 16.78 MB
    const size_t opartB = (size_t)2 * 2 * S_ * SR * 4;       // 33.55 MB
    const size_t mlB    = (size_t)2 * 2 * HH * S_ * 2 * 4;   // 1.05 MB
    if (ws_size >= kvB + opartB + mlB) {
        short* kbuf  = (short*)d_ws;
        short* vtbuf = kbuf + elems;
        float* opart = (float*)((char*)d_ws + kvB);
        float* mlbuf = opart + (size_t)2 * 2 * S_ * SR;
        prep_k<<<dim3(2048), dim3(256), 0, stream>>>(k, kbuf);
        prep_vt<<<dim3(1024), dim3(256), 0, stream>>>(v, vtbuf);
        fattn_split<<<dim3(1024), dim3(256), 0, stream>>>(q, kbuf, vtbuf, opart, mlbuf);
        merge_k<<<dim3(4096), dim3(256), 0, stream>>>(opart, mlbuf, out);
    } else {
        fattn_fb<<<dim3(512), dim3(256), 0, stream>>>(q, k, v, out);
    }
}

// Round 6
// 82.937 us; speedup vs baseline: 1.1654x; 1.1654x over previous
//
#include <hip/hip_runtime.h>

// FlashAttention fwd: B=2, S=2048, H=16, D=64, fp32 in/out, non-causal.
// R5: no KV-split (512 blocks, full S per block). KVBLK=128 per phase
// (2x64 subtiles, double-buffered 64KB LDS, 2 blocks/CU). P^T B-frags via
// permlane32_swap (1 op, both words). Prep converts K->bf16 [b][h][s][d],
// V->bf16^T [b][h][d][s]; staging via global_load_lds (pre-swizzled src).

#define S_  2048
#define HH  16
#define DD  64
#define QT  128
#define SR  1024   // H*D floats per token row

typedef __attribute__((ext_vector_type(8)))  short short8;
typedef __attribute__((ext_vector_type(16))) float f32x16;
typedef __attribute__((ext_vector_type(2)))  unsigned uint2v;

__device__ __forceinline__ unsigned short f2bf(float f) {
    unsigned int u = __float_as_uint(f);
    u += 0x7fffu + ((u >> 16) & 1u);   // RNE
    return (unsigned short)(u >> 16);
}

__device__ __forceinline__ unsigned pkbf(float lo, float hi) {
    unsigned r;
    asm("v_cvt_pk_bf16_f32 %0, %1, %2" : "=v"(r) : "v"(lo), "v"(hi));
    return r;
}

__device__ __forceinline__ short8 cvt8(float4 a, float4 b) {
    union { unsigned u[4]; short8 v; } r;
    r.u[0] = pkbf(a.x, a.y); r.u[1] = pkbf(a.z, a.w);
    r.u[2] = pkbf(b.x, b.y); r.u[3] = pkbf(b.z, b.w);
    return r.v;
}

__device__ __forceinline__ f32x16 mfma32(short8 a, short8 b, f32x16 c) {
    return __builtin_amdgcn_mfma_f32_32x32x16_bf16(a, b, c, 0, 0, 0);
}

__device__ __forceinline__ void gload16(const void* g, void* l) {
    __builtin_amdgcn_global_load_lds(
        (const __attribute__((address_space(1))) void*)g,
        (__attribute__((address_space(3))) void*)l, 16, 0, 0);
}

__device__ __forceinline__ float mx3(float a, float b, float c) {
    return fmaxf(fmaxf(a, b), c);   // clang fuses to v_max3_f32
}

// Pairwise half-wave exchange: given a = pk-pair word for kv-group g0 (own
// hi-half), b = word for kv-group g0+1, produce lo = word for B-frag u[even]
// and hw = word for u[even+2]. permlane32_swap: ret0=[a.lo,b.lo], ret1=[a.hi,b.hi].
__device__ __forceinline__ void mk_pf(unsigned a, unsigned b,
                                      unsigned& lo, unsigned& hw, int hi) {
#if __has_builtin(__builtin_amdgcn_permlane32_swap)
    uint2v r = __builtin_amdgcn_permlane32_swap(a, b, false, false);
    lo = r[0]; hw = r[1];
#else
    unsigned rX = __shfl_xor(hi ? a : b, 32);   // R4-verified construction
    lo = hi ? rX : a;
    hw = hi ? b  : rX;
#endif
}

// ---------------- prep kernels (R3-verified) ----------------

__global__ __launch_bounds__(256)
void prep_k(const float* __restrict__ k, short* __restrict__ kb) {
    const int gid = blockIdx.x * 256 + threadIdx.x;   // 524288 total
    const int d0 = (gid & 7) * 8;
    const int s  = (gid >> 3) & (S_ - 1);
    const int h  = (gid >> 14) & (HH - 1);
    const int b  = gid >> 18;
    const float* src = k + ((size_t)(b * S_ + s) * SR + h * DD + d0);
    float4 a = *(const float4*)src, bb = *(const float4*)(src + 4);
    *(short8*)&kb[((size_t)(b * HH + h) * S_ + s) * DD + d0] = cvt8(a, bb);
}

__global__ __launch_bounds__(256)
void prep_vt(const float* __restrict__ v, short* __restrict__ vt) {
    __shared__ short lt[64][72];   // +8 pad
    const int t = blockIdx.x & 31;
    const int h = (blockIdx.x >> 5) & 15;
    const int b = blockIdx.x >> 9;
    const int tid = threadIdx.x;
    const int c8 = tid & 7, r0 = tid >> 3;
    #pragma unroll
    for (int rr = 0; rr < 2; ++rr) {
        const int row = r0 + rr * 32;
        const float* src = v + ((size_t)(b * S_ + t * 64 + row) * SR + h * DD + c8 * 8);
        float4 a = *(const float4*)src, bb = *(const float4*)(src + 4);
        *(short8*)&lt[row][c8 * 8] = cvt8(a, bb);
    }
    __syncthreads();
    const int d = tid >> 2, q4 = tid & 3;
    short tmp[16];
    #pragma unroll
    for (int i = 0; i < 16; ++i) tmp[i] = lt[q4 * 16 + i][d];
    short8* dst = (short8*)&vt[((size_t)(b * HH + h) * DD + d) * S_ + t * 64 + q4 * 16];
    dst[0] = *(short8*)&tmp[0];
    dst[1] = *(short8*)&tmp[8];
}

// ---------------- main attention kernel ----------------

__global__ __launch_bounds__(256, 2)
void fattn_main(const float* __restrict__ q, const short* __restrict__ kb,
                const short* __restrict__ vtb, float* __restrict__ out) {
    // [dbuf][sub][64*64] bf16: K[kv][d] (granule g holds chunk g^(kv&7)),
    // V^T[d][kv] (granule g holds kv-chunk g^(d&7)). 32KB + 32KB.
    __shared__ short lk[2 * 2 * 4096];
    __shared__ short lvT[2 * 2 * 4096];

    const int tid  = threadIdx.x;
    const int lane = tid & 63;
    const int w    = tid >> 6;
    const int c    = lane & 31;
    const int hi   = lane >> 5;

    // XCD swizzle (512 = 8 XCDs x 64): 16 q-tile blocks of one (b,h) -> one XCD.
    const int bid0 = blockIdx.x;
    const int bid  = ((bid0 & 7) << 6) | (bid0 >> 3);
    const int qt  = bid & 15;
    const int h   = (bid >> 4) & 15;
    const int b   = bid >> 8;
    const int bh  = b * HH + h;

    const int qrow = qt * QT + w * 32 + c;
    const float sc = 0.125f * 1.4426950408889634f;  // D^-1/2 * log2(e)

    // ---- Q B-fragments: qf[kc][i] = Q[qrow][kc*16 + hi*8 + i] * sc ----
    short8 qf[4];
    {
        const float* qp = q + (size_t)(b * S_ + qrow) * SR + h * DD;
        #pragma unroll
        for (int kc = 0; kc < 4; ++kc) {
            const int d0 = kc * 16 + hi * 8;
            float4 a = *(const float4*)(qp + d0);
            float4 bb = *(const float4*)(qp + d0 + 4);
            a.x *= sc; a.y *= sc; a.z *= sc; a.w *= sc;
            bb.x *= sc; bb.y *= sc; bb.z *= sc; bb.w *= sc;
            qf[kc] = cvt8(a, bb);
        }
    }

    f32x16 o0, o1;
    #pragma unroll
    for (int i = 0; i < 16; ++i) { o0[i] = 0.f; o1[i] = 0.f; }
    float m_run = -1e30f, l_lane = 0.f;

    const short* kbh = kb  + (size_t)bh * S_ * DD;
    const short* vbh = vtb + (size_t)bh * DD * S_;
    const int r8 = lane >> 3;
    const int g8 = lane & 7;

    // Stage phase pp_ (kv tiles 2pp_, 2pp_+1) into dbuf half bufi_.
    // 8 x global_load_lds per wave; source pre-swizzled, LDS linear.
    #define STAGE(pp_, bufi_)                                                   \
        _Pragma("unroll")                                                       \
        for (int sub = 0; sub < 2; ++sub) {                                     \
            const int tile = 2 * (pp_) + sub;                                   \
            _Pragma("unroll")                                                   \
            for (int ss = 0; ss < 2; ++ss) {                                    \
                const int sect = 2 * w + ss;                                    \
                const int row  = sect * 8 + r8;                                 \
                gload16(kbh + (size_t)(tile * 64 + row) * DD + ((g8 ^ (row & 7)) * 8), \
                        &lk[(bufi_) * 8192 + sub * 4096 + sect * 512]);         \
                gload16(vbh + (size_t)row * S_ + tile * 64 + ((g8 ^ (row & 7)) * 8),   \
                        &lvT[(bufi_) * 8192 + sub * 4096 + sect * 512]);        \
            }                                                                   \
        }

    STAGE(0, 0);

    for (int pp = 0; pp < S_ / 128; ++pp) {
        const int cur = pp & 1;
        __syncthreads();   // drains this phase's loads; prev phase reads done
        if (pp + 1 < S_ / 128) { STAGE(pp + 1, cur ^ 1); }

        #pragma unroll
        for (int t2 = 0; t2 < 2; ++t2) {
            const short* lkS = &lk[cur * 8192 + t2 * 4096];
            const short* lvS = &lvT[cur * 8192 + t2 * 4096];

            // ---- S^T = K . Q^T : lane holds S[q=c][kv=(r&3)+8*(r>>2)+4*hi (+32)] ----
            f32x16 s0, s1;
            #pragma unroll
            for (int i = 0; i < 16; ++i) { s0[i] = 0.f; s1[i] = 0.f; }
            __builtin_amdgcn_s_setprio(1);
            #pragma unroll
            for (int kc = 0; kc < 4; ++kc) {
                const int ch = 2 * kc + hi;
                short8 kf0 = *(const short8*)&lkS[c * 64 + ((ch ^ (c & 7)) * 8)];
                short8 kf1 = *(const short8*)&lkS[(32 + c) * 64 + ((ch ^ (c & 7)) * 8)];
                s0 = mfma32(kf0, qf[kc], s0);
                s1 = mfma32(kf1, qf[kc], s1);
            }
            __builtin_amdgcn_s_setprio(0);

            // ---- pmax (max3-shaped tree) ----
            float a0 = mx3(s0[0], s0[1], s0[2]),  a1 = mx3(s0[3], s0[4], s0[5]);
            float a2 = mx3(s0[6], s0[7], s0[8]),  a3 = mx3(s0[9], s0[10], s0[11]);
            float a4 = mx3(s0[12], s0[13], s0[14]);
            float a5 = mx3(s1[0], s1[1], s1[2]),  a6 = mx3(s1[3], s1[4], s1[5]);
            float a7 = mx3(s1[6], s1[7], s1[8]),  a8 = mx3(s1[9], s1[10], s1[11]);
            float a9 = mx3(s1[12], s1[13], s1[14]);
            float b0 = mx3(a0, a1, s0[15]), b1 = mx3(a2, a3, a4);
            float b2 = mx3(a5, a6, s1[15]), b3 = mx3(a7, a8, a9);
            float pmax = fmaxf(fmaxf(b0, b1), fmaxf(b2, b3));
            pmax = fmaxf(pmax, __shfl_xor(pmax, 32));

            if (__ballot(pmax > m_run + 8.0f)) {   // defer-max THR=8
                const float mn = fmaxf(m_run, pmax);
                const float corr = exp2f(m_run - mn);
                m_run = mn;
                l_lane *= corr;
                #pragma unroll
                for (int i = 0; i < 16; ++i) { o0[i] *= corr; o1[i] *= corr; }
            }

            // ---- exp2 -> pack -> in-register P^T frags -> PV ----
            float rs = 0.f;
            #pragma unroll
            for (int gidx = 0; gidx < 2; ++gidx) {
                const f32x16& sg = gidx ? s1 : s0;
                float p[16];
                #pragma unroll
                for (int i = 0; i < 16; ++i) p[i] = exp2f(sg[i] - m_run);
                rs += (((p[0] + p[1]) + (p[2] + p[3])) + ((p[4] + p[5]) + (p[6] + p[7])))
                    + (((p[8] + p[9]) + (p[10] + p[11])) + ((p[12] + p[13]) + (p[14] + p[15])));
                // pA[sp] = P[kv = 8sp+4hi, +1], pB[sp] = P[kv = 8sp+4hi+2, +3]
                unsigned pA[4], pB[4];
                #pragma unroll
                for (int sp = 0; sp < 4; ++sp) {
                    pA[sp] = pkbf(p[4 * sp + 0], p[4 * sp + 1]);
                    pB[sp] = pkbf(p[4 * sp + 2], p[4 * sp + 3]);
                }
                union PU { unsigned u[4]; short8 v; } pf[2];
                #pragma unroll
                for (int kcg = 0; kcg < 2; ++kcg) {
                    unsigned loA, hwA, loB, hwB;
                    mk_pf(pA[2 * kcg], pA[2 * kcg + 1], loA, hwA, hi);
                    mk_pf(pB[2 * kcg], pB[2 * kcg + 1], loB, hwB, hi);
                    pf[kcg].u[0] = loA; pf[kcg].u[1] = loB;
                    pf[kcg].u[2] = hwA; pf[kcg].u[3] = hwB;
                }
                // ---- O^T += V^T . P^T for this group's two 16-kv chunks ----
                __builtin_amdgcn_s_setprio(1);
                #pragma unroll
                for (int kcg = 0; kcg < 2; ++kcg) {
                    const int ch = 4 * gidx + 2 * kcg + hi;
                    const int gsel = (ch ^ (c & 7)) * 8;
                    short8 va0 = *(const short8*)&lvS[c * 64 + gsel];
                    short8 va1 = *(const short8*)&lvS[(32 + c) * 64 + gsel];
                    o0 = mfma32(va0, pf[kcg].v, o0);
                    o1 = mfma32(va1, pf[kcg].v, o1);
                }
                __builtin_amdgcn_s_setprio(0);
            }
            l_lane += rs;   // cross-lane reduce deferred to epilogue
        }
    }
    #undef STAGE

    // ---- Epilogue: O / l ----
    const float l_tot = l_lane + __shfl_xor(l_lane, 32);
    const float inv = 1.0f / l_tot;
    float* orow = out + (size_t)(b * S_ + qrow) * SR + h * DD;
    #pragma unroll
    for (int sp = 0; sp < 4; ++sp) {
        float4 st0, st1;
        st0.x = o0[4 * sp + 0] * inv; st0.y = o0[4 * sp + 1] * inv;
        st0.z = o0[4 * sp + 2] * inv; st0.w = o0[4 * sp + 3] * inv;
        st1.x = o1[4 * sp + 0] * inv; st1.y = o1[4 * sp + 1] * inv;
        st1.z = o1[4 * sp + 2] * inv; st1.w = o1[4 * sp + 3] * inv;
        *(float4*)(orow + 8 * sp + 4 * hi)      = st0;
        *(float4*)(orow + 32 + 8 * sp + 4 * hi) = st1;
    }
}

// ---------------- fallback (R2-verified, used if ws too small) ----------------

__global__ __launch_bounds__(256, 2)
void fattn_fb(const float* __restrict__ q, const float* __restrict__ k,
              const float* __restrict__ v, float* __restrict__ out) {
    __shared__ short lk[64 * DD];
    __shared__ short lvT[DD * 64];
    __shared__ short lp[4][32 * 64];

    const int tid  = threadIdx.x;
    const int lane = tid & 63;
    const int w    = tid >> 6;
    const int c    = lane & 31;
    const int hi   = lane >> 5;

    const int bid = blockIdx.x;
    const int qt  = bid & 15;
    const int h   = (bid >> 4) & 15;
    const int b   = bid >> 8;

    const int qrow = qt * QT + w * 32 + c;
    const float sc = 0.125f * 1.4426950408889634f;

    short8 qf[4];
    {
        const float* qp = q + (size_t)(b * S_ + qrow) * SR + h * DD;
        #pragma unroll
        for (int kc = 0; kc < 4; ++kc) {
            const int d0 = kc * 16 + hi * 8;
            float4 a = *(const float4*)(qp + d0);
            float4 bb = *(const float4*)(qp + d0 + 4);
            a.x *= sc; a.y *= sc; a.z *= sc; a.w *= sc;
            bb.x *= sc; bb.y *= sc; bb.z *= sc; bb.w *= sc;
            qf[kc] = cvt8(a, bb);
        }
    }

    f32x16 o0, o1;
    #pragma unroll
    for (int i = 0; i < 16; ++i) { o0[i] = 0.f; o1[i] = 0.f; }
    float m_run = -1e30f, l_run = 0.f;

    const float* kb = k + (size_t)b * S_ * SR + h * DD;
    const float* vb = v + (size_t)b * S_ * SR + h * DD;

    for (int t = 0; t < S_ / 64; ++t) {
        __syncthreads();
        for (int cc = w; cc < 8; cc += 4) {
            const size_t gro = (size_t)(t * 64 + lane) * SR + cc * 8;
            const float4* kp = (const float4*)(kb + gro);
            float4 k0 = kp[0], k1 = kp[1];
            *(short8*)&lk[lane * 64 + ((cc ^ (lane & 7)) * 8)] = cvt8(k0, k1);
            const float4* vp = (const float4*)(vb + gro);
            float4 v0 = vp[0], v1 = vp[1];
            float vv[8] = {v0.x, v0.y, v0.z, v0.w, v1.x, v1.y, v1.z, v1.w};
            #pragma unroll
            for (int i = 0; i < 8; ++i) {
                const int d = cc * 8 + i;
                lvT[d * 64 + (((lane >> 3) ^ (d & 7)) * 8) + (lane & 7)] =
                    (short)f2bf(vv[i]);
            }
        }
        __syncthreads();

        f32x16 s0, s1;
        #pragma unroll
        for (int i = 0; i < 16; ++i) { s0[i] = 0.f; s1[i] = 0.f; }
        #pragma unroll
        for (int kc = 0; kc < 4; ++kc) {
            const int ch = 2 * kc + hi;
            short8 kf0 = *(const short8*)&lk[c * 64 + ((ch ^ (c & 7)) * 8)];
            short8 kf1 = *(const short8*)&lk[(32 + c) * 64 + ((ch ^ (c & 7)) * 8)];
            s0 = mfma32(kf0, qf[kc], s0);
            s1 = mfma32(kf1, qf[kc], s1);
        }

        float pmax = fmaxf(s0[0], s0[1]);
        #pragma unroll
        for (int i = 2; i < 16; ++i) pmax = fmaxf(pmax, s0[i]);
        #pragma unroll
        for (int i = 0; i < 16; ++i) pmax = fmaxf(pmax, s1[i]);
        pmax = fmaxf(pmax, __shfl_xor(pmax, 32));

        if (__ballot(pmax > m_run + 8.0f)) {
            const float mn = fmaxf(m_run, pmax);
            const float corr = exp2f(m_run - mn);
            m_run = mn;
            l_run *= corr;
            #pragma unroll
            for (int i = 0; i < 16; ++i) { o0[i] *= corr; o1[i] *= corr; }
        }

        float p0[16], p1[16];
        float rs = 0.f;
        #pragma unroll
        for (int i = 0; i < 16; ++i) { p0[i] = exp2f(s0[i] - m_run); rs += p0[i]; }
        #pragma unroll
        for (int i = 0; i < 16; ++i) { p1[i] = exp2f(s1[i] - m_run); rs += p1[i]; }
        rs += __shfl_xor(rs, 32);
        l_run += rs;

        #pragma unroll
        for (int sp = 0; sp < 4; ++sp) {
            uint2v w0;
            w0[0] = pkbf(p0[4 * sp + 0], p0[4 * sp + 1]);
            w0[1] = pkbf(p0[4 * sp + 2], p0[4 * sp + 3]);
            *(uint2v*)&lp[w][c * 64 + ((sp ^ (c & 7)) * 8) + hi * 4] = w0;
            uint2v w1;
            w1[0] = pkbf(p1[4 * sp + 0], p1[4 * sp + 1]);
            w1[1] = pkbf(p1[4 * sp + 2], p1[4 * sp + 3]);
            *(uint2v*)&lp[w][c * 64 + (((4 + sp) ^ (c & 7)) * 8) + hi * 4] = w1;
        }

        #pragma unroll
        for (int kc = 0; kc < 4; ++kc) {
            const int gsel = ((2 * kc + hi) ^ (c & 7)) * 8;
            short8 pa  = *(const short8*)&lp[w][c * 64 + gsel];
            short8 va0 = *(const short8*)&lvT[c * 64 + gsel];
            short8 va1 = *(const short8*)&lvT[(32 + c) * 64 + gsel];
            o0 = mfma32(va0, pa, o0);
            o1 = mfma32(va1, pa, o1);
        }
    }

    const float inv = 1.0f / l_run;
    float* orow = out + (size_t)(b * S_ + qrow) * SR + h * DD;
    #pragma unroll
    for (int sp = 0; sp < 4; ++sp) {
        float4 st0, st1;
        st0.x = o0[4 * sp + 0] * inv; st0.y = o0[4 * sp + 1] * inv;
        st0.z = o0[4 * sp + 2] * inv; st0.w = o0[4 * sp + 3] * inv;
        st1.x = o1[4 * sp + 0] * inv; st1.y = o1[4 * sp + 1] * inv;
        st1.z = o1[4 * sp + 2] * inv; st1.w = o1[4 * sp + 3] * inv;
        *(float4*)(orow + 8 * sp + 4 * hi)      = st0;
        *(float4*)(orow + 32 + 8 * sp + 4 * hi) = st1;
    }
}

extern "C" void kernel_launch(void* const* d_in, const int* in_sizes, int n_in,
                              void* d_out, int out_size, void* d_ws, size_t ws_size,
                              hipStream_t stream) {
    const float* q = (const float*)d_in[0];
    const float* k = (const float*)d_in[1];
    const float* v = (const float*)d_in[2];
    float* out = (float*)d_out;

    const size_t elems = (size_t)2 * HH * S_ * DD;       // 4.19M per tensor
    const size_t kvB   = elems * 2 * sizeof(short);      // Kb + VTb = 16.78 MB
    if (ws_size >= kvB) {
        short* kbuf  = (short*)d_ws;
        short* vtbuf = kbuf + elems;
        prep_k<<<dim3(2048), dim3(256), 0, stream>>>(k, kbuf);
        prep_vt<<<dim3(1024), dim3(256), 0, stream>>>(v, vtbuf);
        fattn_main<<<dim3(512), dim3(256), 0, stream>>>(q, kbuf, vtbuf, out);
    } else {
        fattn_fb<<<dim3(512), dim3(256), 0, stream>>>(q, k, v, out);
    }
}